// Round 1
// baseline (277.477 us; speedup 1.0000x reference)
//
#include <hip/hip_runtime.h>

// C3D loss, MI355X. B=4, H=352, W=1216, R=2, ELL=0.05 -> inv2ell2=200.
#define Bc   4
#define Hc   352
#define Wc   1216
#define HWc  (Hc * Wc)
#define NPIX (Bc * HWc)

struct F3 { float x, y, z; };

// xyz = xy1 * depth, with zero outside the image (matches jnp.pad zero-fill)
__device__ inline F3 get_xyz(const float* __restrict__ depth,
                             const float* __restrict__ xy1,
                             int b, int i, int j) {
    F3 r;
    if ((unsigned)i >= (unsigned)Hc || (unsigned)j >= (unsigned)Wc) {
        r.x = 0.f; r.y = 0.f; r.z = 0.f; return r;
    }
    int off = i * Wc + j;
    float d = depth[b * HWc + off];
    const float* x = xy1 + (size_t)b * 3 * HWc + off;
    r.x = x[0] * d;
    r.y = x[HWc] * d;
    r.z = x[2 * HWc] * d;
    return r;
}

// n = normalize(cross(gx, gy)), gx/gy = 0.5*(right-left / down-up), zero-padded
__device__ inline F3 get_normal(const float* __restrict__ depth,
                                const float* __restrict__ xy1,
                                int b, int i, int j) {
    F3 xr = get_xyz(depth, xy1, b, i, j + 1);
    F3 xl = get_xyz(depth, xy1, b, i, j - 1);
    F3 xd = get_xyz(depth, xy1, b, i + 1, j);
    F3 xu = get_xyz(depth, xy1, b, i - 1, j);
    float gxx = 0.5f * (xr.x - xl.x), gxy = 0.5f * (xr.y - xl.y), gxz = 0.5f * (xr.z - xl.z);
    float gyx = 0.5f * (xd.x - xu.x), gyy = 0.5f * (xd.y - xu.y), gyz = 0.5f * (xd.z - xu.z);
    F3 n;
    n.x = gxy * gyz - gxz * gyy;
    n.y = gxz * gyx - gxx * gyz;
    n.z = gxx * gyy - gxy * gyx;
    float inv = 1.0f / (sqrtf(n.x * n.x + n.y * n.y + n.z * n.z) + 1e-8f);
    n.x *= inv; n.y *= inv; n.z *= inv;
    return n;
}

__global__ __launch_bounds__(256) void c3d_main(
    const float* __restrict__ dp,    // depth_pred [B,1,H,W]
    const float* __restrict__ dg,    // depth_gt   [B,1,H,W]
    const float* __restrict__ xy1,   // xy1_grid   [B,3,H,W]
    const int*   __restrict__ mask,  // mask       [B,1,H,W] (0/1)
    float* __restrict__ acc)         // acc[0]=total, acc[1]=n_valid
{
    int p = blockIdx.x * 256 + threadIdx.x;
    int lane = threadIdx.x & 63;
    int wid  = threadIdx.x >> 6;

    bool valid = false;
    if (p < NPIX) valid = (mask[p] != 0);

    unsigned long long bal = __ballot(valid);
    int cnt = __popcll(bal);
    float waveTot = 0.f;

    // Wave-cooperative: each masked pixel is processed by lanes 0..24
    while (bal) {
        int src = __ffsll((unsigned long long)bal) - 1;
        bal &= (bal - 1);
        int sp = __shfl(p, src);
        int b   = sp / HWc;
        int rem = sp - b * HWc;
        int i   = rem / Wc;
        int j   = rem - i * Wc;

        float contrib = 0.f;
        if (lane < 25) {
            int dy = lane / 5 - 2;
            int dx = lane % 5 - 2;
            int ii = i + dy, jj = j + dx;
            if ((unsigned)ii < (unsigned)Hc && (unsigned)jj < (unsigned)Wc) {
                F3 xg = get_xyz(dg, xy1, b, i, j);       // same for all 25 lanes (SIMT: ~1x cost)
                F3 ng = get_normal(dg, xy1, b, i, j);
                F3 xp = get_xyz(dp, xy1, b, ii, jj);
                F3 np = get_normal(dp, xy1, b, ii, jj);
                float ddx = xp.x - xg.x, ddy = xp.y - xg.y, ddz = xp.z - xg.z;
                float d2 = ddx * ddx + ddy * ddy + ddz * ddz;
                float kg = expf(-200.f * d2);
                float nk = fabsf(np.x * ng.x + np.y * ng.y + np.z * ng.z);
                contrib = kg * (0.1f + 1.9f * nk);
            }
        }
        // wave-64 reduction into lane 0
        for (int off = 32; off > 0; off >>= 1)
            contrib += __shfl_down(contrib, off);
        if (lane == 0) waveTot += contrib;
    }

    __shared__ float sTot[4];
    __shared__ int   sCnt[4];
    if (lane == 0) { sTot[wid] = waveTot; sCnt[wid] = cnt; }
    __syncthreads();
    if (threadIdx.x == 0) {
        float t = sTot[0] + sTot[1] + sTot[2] + sTot[3];
        int   c = sCnt[0] + sCnt[1] + sCnt[2] + sCnt[3];
        if (t != 0.f) atomicAdd(acc, t);
        if (c)        atomicAdd(acc + 1, (float)c);  // counts < 2^24 -> exact in f32
    }
}

__global__ void c3d_final(const float* __restrict__ acc, float* __restrict__ out) {
    out[0] = -acc[0] / (acc[1] + 1e-8f);
}

extern "C" void kernel_launch(void* const* d_in, const int* in_sizes, int n_in,
                              void* d_out, int out_size, void* d_ws, size_t ws_size,
                              hipStream_t stream) {
    const float* depth_pred = (const float*)d_in[0];
    const float* depth_gt   = (const float*)d_in[1];
    const float* xy1_grid   = (const float*)d_in[2];
    // d_in[3] = K, unused by the reference math
    const int*   mask       = (const int*)d_in[4];
    float* out = (float*)d_out;
    float* acc = (float*)d_ws;

    hipMemsetAsync(acc, 0, 2 * sizeof(float), stream);  // ws is poisoned 0xAA each call
    int nblocks = (NPIX + 255) / 256;  // exactly 6688
    c3d_main<<<dim3(nblocks), dim3(256), 0, stream>>>(depth_pred, depth_gt, xy1_grid, mask, acc);
    c3d_final<<<1, 1, 0, stream>>>(acc, out);
}